// Round 3
// baseline (4660.992 us; speedup 1.0000x reference)
//
#include <hip/hip_runtime.h>
#include <hip/hip_cooperative_groups.h>
#include <math.h>

namespace cg = cooperative_groups;

#define NN   65536
#define NI   16384
#define NH   512
#define NBLK 256
#define NTHR 1024
#define RCH  4096   // rows per block in GEMV1 (16 row-chunks x 16 col-chunks)

constexpr float F_T    = 0.01f;
constexpr float F_ATOL = 1e-7f;
constexpr float F_RTOL = 1e-5f;

// dopri5 embedded-error coefficients
constexpr float CE1 = (float)(35.0/384.0 - 5179.0/57600.0);
constexpr float CE3 = (float)(500.0/1113.0 - 7571.0/16695.0);
constexpr float CE4 = (float)(125.0/192.0 - 393.0/640.0);
constexpr float CE5 = (float)(-2187.0/6784.0 + 92097.0/339200.0);
constexpr float CE6 = (float)(11.0/84.0 - 187.0/2100.0);
constexpr float CE7 = (float)(-1.0/40.0);

// stage-input combo coefficients (row s-1 makes k_{s+1}; row 5 = y5/B row).
// constexpr (not __constant__) so template-unrolled indexing folds at compile time.
constexpr float COEFC[6][6] = {
  {(float)(1.0/5.0), 0.f, 0.f, 0.f, 0.f, 0.f},
  {(float)(3.0/40.0), (float)(9.0/40.0), 0.f, 0.f, 0.f, 0.f},
  {(float)(44.0/45.0), (float)(-56.0/15.0), (float)(32.0/9.0), 0.f, 0.f, 0.f},
  {(float)(19372.0/6561.0), (float)(-25360.0/2187.0), (float)(64448.0/6561.0),
   (float)(-212.0/729.0), 0.f, 0.f},
  {(float)(9017.0/3168.0), (float)(-355.0/33.0), (float)(46732.0/5247.0),
   (float)(49.0/176.0), (float)(-5103.0/18656.0), 0.f},
  {(float)(35.0/384.0), 0.f, (float)(500.0/1113.0), (float)(125.0/192.0),
   (float)(-2187.0/6784.0), (float)(11.0/84.0)}
};

// Persistent device scratch. Everything is written before it is read on every
// call (no atomics anywhere -> fully deterministic across graph replays).
__device__ __attribute__((aligned(16))) float g_y0[NN];
__device__ __attribute__((aligned(16))) float g_bufA[NN];
__device__ __attribute__((aligned(16))) float g_bufB[NN];
__device__ __attribute__((aligned(16))) float g_k2[NN];
__device__ __attribute__((aligned(16))) float g_k3[NN];
__device__ __attribute__((aligned(16))) float g_k4[NN];
__device__ __attribute__((aligned(16))) float g_k5[NN];
__device__ __attribute__((aligned(16))) float g_k6[NN];
__device__ __attribute__((aligned(16))) float g_kA[NN];   // k1/k7 swap pair
__device__ __attribute__((aligned(16))) float g_kB[NN];
__device__ __attribute__((aligned(16))) float g_ypart[16][NH]; // y@W1 partials per row-chunk
__device__ __attribute__((aligned(16))) float g_ipart[16][NH]; // I@W1[NN:] partials (computed once)
__device__ __attribute__((aligned(16))) float g_h2v[NH];       // h1@W2 (pre-tanh, pre-bias)
__device__ __attribute__((aligned(16))) float g_errpart[NBLK]; // per-block err^2 partials

__device__ __forceinline__ float4 ld4(const float* p) { return *(const float4*)p; }
__device__ __forceinline__ void f4acc(float4& a, const float4& b) {
  a.x += b.x; a.y += b.y; a.z += b.z; a.w += b.w;
}

struct Ptrs { const float *x, *W1, *b1, *W2, *b2, *W3, *b3; };

// Full release/acquire grid barrier: fences force vmcnt drain + L2 writeback
// (release) and L2 invalidate (acquire) around the cooperative barrier —
// per-XCD L2s are not coherent, grid.sync alone proved insufficient (R0->R1
// post-timing divergence of 0.447 vs first-call pass).
__device__ __forceinline__ void gsync(cg::grid_group& g) {
  __threadfence();
  g.sync();
  __threadfence();
}

// One drift evaluation, 3 phases. SIDX: 0 = f(y) (k1); 1..5 = k2..k6 stage
// inputs; 6 = y5/B-row (also persists y5, computes k7 + embedded error).
template<int SIDX, bool DO_ERR>
__device__ void run_stage(cg::grid_group& grid, const int tid, const int bid,
                          const Ptrs& P, const float* ycur, const float heff,
                          const float* k1p, float* outk, float* y5buf,
                          float* sA, float4* sRed)
{
  const int cc      = bid >> 4;          // col chunk (16 x 32 cols of W1)
  const int rowbase = (bid & 15) * RCH;  // row chunk (16 x 4096 rows)

  // ---------- Phase A: GEMV1 partials  ypart[rc][c] = sum_i ytmp[i]*W1[i][c] ----------
  {
    for (int j = tid; j < RCH; j += NTHR) {
      const int i = rowbase + j;
      float v;
      if constexpr (SIDX == 0) {
        v = ycur[i];
      } else {
        const float* kp[6] = {k1p, g_k2, g_k3, g_k4, g_k5, g_k6};
        float s = 0.f;
        #pragma unroll
        for (int m = 0; m < 6; ++m) {
          const float cf = COEFC[SIDX - 1][m];   // compile-time after unroll
          if (cf != 0.f) s += cf * kp[m][i];
        }
        v = ycur[i] + heff * s;
      }
      sA[j] = v;
      if constexpr (SIDX == 6) { if (cc == 0) y5buf[i] = v; }  // persist y5 once
    }
    __syncthreads();
    const int q = tid & 7, rg = tid >> 3;
    const int col = cc * 32 + q * 4;
    const float* wp = P.W1 + (size_t)rowbase * NH + col;
    float4 a0 = make_float4(0.f, 0.f, 0.f, 0.f);
    float4 a1 = make_float4(0.f, 0.f, 0.f, 0.f);
    #pragma unroll
    for (int it = 0; it < 16; ++it) {          // dual streams: 2x loads in flight
      const int r0 = rg + it * 256, r1 = r0 + 128;
      const float y0v = sA[r0], y1v = sA[r1];
      const float4 w0 = ld4(wp + (size_t)r0 * NH);
      const float4 w1 = ld4(wp + (size_t)r1 * NH);
      a0.x += y0v * w0.x; a0.y += y0v * w0.y; a0.z += y0v * w0.z; a0.w += y0v * w0.w;
      a1.x += y1v * w1.x; a1.y += y1v * w1.y; a1.z += y1v * w1.z; a1.w += y1v * w1.w;
    }
    f4acc(a0, a1);
    sRed[tid] = a0;
    __syncthreads();
    for (int off = 512; off >= 8; off >>= 1) {
      if (tid < off) { float4 a = sRed[tid]; f4acc(a, sRed[tid + off]); sRed[tid] = a; }
      __syncthreads();
    }
    if (tid < 8) *(float4*)&g_ypart[bid & 15][cc * 32 + tid * 4] = sRed[tid];
  }
  gsync(grid);

  // ---------- Phase B: h1 = tanh(sum partials + b1); h2pre = h1 @ W2 ----------
  if (bid < 8) {
    if (tid < NH) {
      float pre = P.b1[tid];
      #pragma unroll
      for (int rc = 0; rc < 16; ++rc) pre += g_ypart[rc][tid];
      #pragma unroll
      for (int rc = 0; rc < 16; ++rc) pre += g_ipart[rc][tid];
      sA[tid] = tanhf(pre);
    }
    __syncthreads();
    float* sB = (float*)sRed;
    const int cl = tid & 63, kg = tid >> 6;    // 16 k-groups x 64 cols
    const int c = bid * 64 + cl;
    float acc = 0.f;
    #pragma unroll
    for (int m = 0; m < 32; ++m) {
      const int k = kg * 32 + m;
      acc += sA[k] * P.W2[(size_t)k * NH + c];
    }
    sB[tid] = acc;
    __syncthreads();
    for (int off = 512; off >= 64; off >>= 1) {
      if (tid < off) sB[tid] += sB[tid + off];
      __syncthreads();
    }
    if (tid < 64) g_h2v[bid * 64 + tid] = sB[tid];
  }
  gsync(grid);

  // ---------- Phase C: outk[n] = tanh(h2pre+b2) @ W3 + b3 ----------
  {
    if (tid < NH) sA[tid] = tanhf(g_h2v[tid] + P.b2[tid]);
    __syncthreads();
    const int cl = tid & 63, kg = tid >> 6;    // 16 k-groups x 64 col-quads
    const int n = bid * 256 + cl * 4;
    float4 a0 = make_float4(0.f, 0.f, 0.f, 0.f);
    float4 a1 = make_float4(0.f, 0.f, 0.f, 0.f);
    #pragma unroll
    for (int m = 0; m < 16; ++m) {             // dual streams
      const int k0 = kg * 32 + m, k1i = k0 + 16;
      const float h0 = sA[k0], h1 = sA[k1i];
      const float4 w0 = ld4(P.W3 + (size_t)k0 * NN + n);
      const float4 w1 = ld4(P.W3 + (size_t)k1i * NN + n);
      a0.x += h0 * w0.x; a0.y += h0 * w0.y; a0.z += h0 * w0.z; a0.w += h0 * w0.w;
      a1.x += h1 * w1.x; a1.y += h1 * w1.y; a1.z += h1 * w1.z; a1.w += h1 * w1.w;
    }
    f4acc(a0, a1);
    sRed[tid] = a0;
    __syncthreads();
    for (int off = 512; off >= 64; off >>= 1) {
      if (tid < off) { float4 a = sRed[tid]; f4acc(a, sRed[tid + off]); sRed[tid] = a; }
      __syncthreads();
    }
    float ss = 0.f;
    if (tid < 64) {
      float4 r = sRed[tid];
      const int nn = bid * 256 + tid * 4;
      const float4 b3v = ld4(P.b3 + nn);
      r.x += b3v.x; r.y += b3v.y; r.z += b3v.z; r.w += b3v.w;
      *(float4*)(outk + nn) = r;
      if constexpr (DO_ERR) {                  // fused embedded-error pass (r == k7)
        const float4 k1v = ld4(k1p + nn);
        const float4 k3v = ld4(g_k3 + nn);
        const float4 k4v = ld4(g_k4 + nn);
        const float4 k5v = ld4(g_k5 + nn);
        const float4 k6v = ld4(g_k6 + nn);
        const float4 yv  = ld4(ycur + nn);
        const float4 y5v = ld4(y5buf + nn);
        #define ERRC(c) { \
          const float e = heff*(CE1*k1v.c + CE3*k3v.c + CE4*k4v.c + \
                                CE5*k5v.c + CE6*k6v.c + CE7*r.c); \
          const float sc = F_ATOL + F_RTOL*fmaxf(fabsf(yv.c), fabsf(y5v.c)); \
          const float qq = e / sc; ss += qq * qq; }
        ERRC(x) ERRC(y) ERRC(z) ERRC(w)
        #undef ERRC
      }
    }
    if constexpr (DO_ERR) {                    // deterministic per-block partial
      __syncthreads();
      if (tid < 64) sA[tid] = ss;
      __syncthreads();
      if (tid == 0) {
        float s = 0.f;
        for (int i2 = 0; i2 < 64; ++i2) s += sA[i2];
        g_errpart[bid] = s;
      }
    }
  }
  gsync(grid);
}

__global__ void __launch_bounds__(NTHR, 4)
ode_kernel(const float* __restrict__ x,  const float* __restrict__ W1,
           const float* __restrict__ b1, const float* __restrict__ W2,
           const float* __restrict__ b2, const float* __restrict__ W3,
           const float* __restrict__ b3, float* __restrict__ out)
{
  cg::grid_group grid = cg::this_grid();
  const int tid = threadIdx.x, bid = blockIdx.x;
  __shared__ float  sA[RCH];
  __shared__ float4 sRed[NTHR];
  __shared__ float  sCtl;

  Ptrs P{x, W1, b1, W2, b2, W3, b3};

  // ---- init: y0 = y = x[:,3] (blocks 0..63); I-partials (all blocks) ----
  for (int i = bid * NTHR + tid; i < NN; i += NBLK * NTHR) {
    const float v = x[(size_t)i * 8 + 3];
    g_y0[i] = v; g_bufA[i] = v;
  }
  {
    const int cc = bid >> 4;
    const int rowbase = (bid & 15) * 1024;     // 16 chunks x 1024 input rows
    if (tid < 1024) sA[tid] = x[(size_t)(rowbase + tid) * 8 + 4];
    __syncthreads();
    const int q = tid & 7, rg = tid >> 3;
    const int col = cc * 32 + q * 4;
    const float* wp = W1 + (size_t)(NN + rowbase) * NH + col;
    float4 acc = make_float4(0.f, 0.f, 0.f, 0.f);
    #pragma unroll
    for (int it = 0; it < 8; ++it) {
      const int r = rg + it * 128;
      const float yv = sA[r];
      const float4 w = ld4(wp + (size_t)r * NH);
      acc.x += yv * w.x; acc.y += yv * w.y; acc.z += yv * w.z; acc.w += yv * w.w;
    }
    sRed[tid] = acc;
    __syncthreads();
    for (int off = 512; off >= 8; off >>= 1) {
      if (tid < off) { float4 a = sRed[tid]; f4acc(a, sRed[tid + off]); sRed[tid] = a; }
      __syncthreads();
    }
    if (tid < 8) *(float4*)&g_ipart[bid & 15][cc * 32 + tid * 4] = sRed[tid];
  }
  gsync(grid);

  // ---- dopri5 ----
  float tcur = 0.f, hcur = F_T;
  float* yp  = g_bufA;  float* y5p = g_bufB;
  float* k1p = g_kA;    float* k7p = g_kB;

  // k1 = f(y0) once; thereafter k1_next = take ? k7 : k1 (FSAL, bitwise = ref)
  run_stage<0, false>(grid, tid, bid, P, yp, 0.f, k1p, k1p, y5p, sA, sRed);

  for (int attempt = 0; attempt < 8; ++attempt) {
    if (tcur >= F_T) break;   // grid-uniform: matches ref's done no-op iterations
    const float heff = fminf(hcur, F_T - tcur);

    run_stage<1, false>(grid, tid, bid, P, yp, heff, k1p, g_k2, y5p, sA, sRed);
    run_stage<2, false>(grid, tid, bid, P, yp, heff, k1p, g_k3, y5p, sA, sRed);
    run_stage<3, false>(grid, tid, bid, P, yp, heff, k1p, g_k4, y5p, sA, sRed);
    run_stage<4, false>(grid, tid, bid, P, yp, heff, k1p, g_k5, y5p, sA, sRed);
    run_stage<5, false>(grid, tid, bid, P, yp, heff, k1p, g_k6, y5p, sA, sRed);
    run_stage<6, true >(grid, tid, bid, P, yp, heff, k1p, k7p,  y5p, sA, sRed);

    // deterministic err^2: fixed-order sum of per-block partials, computed
    // redundantly (identically) by every block -> uniform control flow
    if (tid == 0) {
      float s = 0.f;
      for (int b = 0; b < NBLK; ++b) s += g_errpart[b];
      sCtl = s;
    }
    __syncthreads();
    const float e2 = sCtl;

    const float err_norm = sqrtf(e2 * (1.0f / 65536.0f) + 1e-16f);
    const bool accept = err_norm <= 1.0f;
    float fac = 0.9f * powf(err_norm + 1e-10f, -0.2f);
    fac = fminf(fmaxf(fac, 0.2f), 5.0f);
    if (accept) {
      tcur += heff;
      float* tp = yp;  yp  = y5p; y5p = tp;
      tp = k1p; k1p = k7p; k7p = tp;   // FSAL: new k1 == old k7
    }
    hcur = heff * fac;
  }

  if (tid < 256) {
    const int i = bid * 256 + tid;
    out[i] = (yp[i] - g_y0[i]) / F_T;
  }
}

extern "C" void kernel_launch(void* const* d_in, const int* in_sizes, int n_in,
                              void* d_out, int out_size, void* d_ws, size_t ws_size,
                              hipStream_t stream) {
  const float* x  = (const float*)d_in[0];
  const float* W1 = (const float*)d_in[1];
  const float* b1 = (const float*)d_in[2];
  const float* W2 = (const float*)d_in[3];
  const float* b2 = (const float*)d_in[4];
  const float* W3 = (const float*)d_in[5];
  const float* b3 = (const float*)d_in[6];
  float* out = (float*)d_out;
  void* args[] = {(void*)&x, (void*)&W1, (void*)&b1, (void*)&W2, (void*)&b2,
                  (void*)&W3, (void*)&b3, (void*)&out};
  hipLaunchCooperativeKernel((void*)ode_kernel, dim3(NBLK), dim3(NTHR), args, 0, stream);
}

// Round 4
// 1238.801 us; speedup vs baseline: 3.7625x; 3.7625x over previous
//
#include <hip/hip_runtime.h>
#include <math.h>

#define NN   65536
#define NI   16384
#define NH   512
#define NBLK 256
#define NTHR 1024
#define RCH  4096   // rows per block in GEMV1 (16 row-chunks x 16 col-chunks)

constexpr float F_T    = 0.01f;
constexpr float F_ATOL = 1e-7f;
constexpr float F_RTOL = 1e-5f;

// dopri5 embedded-error coefficients
constexpr float CE1 = (float)(35.0/384.0 - 5179.0/57600.0);
constexpr float CE3 = (float)(500.0/1113.0 - 7571.0/16695.0);
constexpr float CE4 = (float)(125.0/192.0 - 393.0/640.0);
constexpr float CE5 = (float)(-2187.0/6784.0 + 92097.0/339200.0);
constexpr float CE6 = (float)(11.0/84.0 - 187.0/2100.0);
constexpr float CE7 = (float)(-1.0/40.0);

// stage-input combo coefficients (row s-1 makes k_{s+1}; row 5 = y5/B row)
constexpr float COEFC[6][6] = {
  {(float)(1.0/5.0), 0.f, 0.f, 0.f, 0.f, 0.f},
  {(float)(3.0/40.0), (float)(9.0/40.0), 0.f, 0.f, 0.f, 0.f},
  {(float)(44.0/45.0), (float)(-56.0/15.0), (float)(32.0/9.0), 0.f, 0.f, 0.f},
  {(float)(19372.0/6561.0), (float)(-25360.0/2187.0), (float)(64448.0/6561.0),
   (float)(-212.0/729.0), 0.f, 0.f},
  {(float)(9017.0/3168.0), (float)(-355.0/33.0), (float)(46732.0/5247.0),
   (float)(49.0/176.0), (float)(-5103.0/18656.0), 0.f},
  {(float)(35.0/384.0), 0.f, (float)(500.0/1113.0), (float)(125.0/192.0),
   (float)(-2187.0/6784.0), (float)(11.0/84.0)}
};

// Persistent device scratch. All cross-block handoff traffic goes through
// agent-scope relaxed atomics (coherent at L3) -> no L2 flush/inv needed.
__device__ __attribute__((aligned(16))) float g_y0[NN];
__device__ __attribute__((aligned(16))) float g_bufA[NN];
__device__ __attribute__((aligned(16))) float g_bufB[NN];
__device__ __attribute__((aligned(16))) float g_k2[NN];
__device__ __attribute__((aligned(16))) float g_k3[NN];
__device__ __attribute__((aligned(16))) float g_k4[NN];
__device__ __attribute__((aligned(16))) float g_k5[NN];
__device__ __attribute__((aligned(16))) float g_k6[NN];
__device__ __attribute__((aligned(16))) float g_kA[NN];   // k1/k7 swap pair
__device__ __attribute__((aligned(16))) float g_kB[NN];
__device__ __attribute__((aligned(16))) float g_ypart[16][NH];
__device__ __attribute__((aligned(16))) float g_ipart[16][NH];
__device__ __attribute__((aligned(16))) float g_h2v[NH];
__device__ __attribute__((aligned(16))) float g_errpart[NBLK];
__device__ int g_bar_count;   // monotonic barrier counter (relative targets, safe across replays)

// ---- coherent (agent-scope, relaxed) access helpers: bypass non-coherent L2 ----
__device__ __forceinline__ float cload(const float* p) {
  return __hip_atomic_load((float*)p, __ATOMIC_RELAXED, __HIP_MEMORY_SCOPE_AGENT);
}
__device__ __forceinline__ void cstore(float* p, float v) {
  __hip_atomic_store(p, v, __ATOMIC_RELAXED, __HIP_MEMORY_SCOPE_AGENT);
}
__device__ __forceinline__ float2 cload2(const float* p) {
  double d = __hip_atomic_load((double*)p, __ATOMIC_RELAXED, __HIP_MEMORY_SCOPE_AGENT);
  return *(float2*)&d;
}
__device__ __forceinline__ void cstore2(float* p, float a, float b) {
  float2 v; v.x = a; v.y = b;
  __hip_atomic_store((double*)p, *(double*)&v, __ATOMIC_RELAXED, __HIP_MEMORY_SCOPE_AGENT);
}
__device__ __forceinline__ float4 cload4(const float* p) {
  float2 a = cload2(p), b = cload2(p + 2);
  return make_float4(a.x, a.y, b.x, b.y);
}

__device__ __forceinline__ float4 ld4(const float* p) { return *(const float4*)p; }
__device__ __forceinline__ void f4acc(float4& a, const float4& b) {
  a.x += b.x; a.y += b.y; a.z += b.z; a.w += b.w;
}

// Fence-free grid barrier. __syncthreads() drains vmcnt(0) for all waves, so
// every prior (coherent) store has reached L3 before the arrival atomic.
// Monotonic counter: the t-th arrival waits for (t/NBLK+1)*NBLK arrivals.
__device__ __forceinline__ void gbar(const int tid) {
  __syncthreads();
  if (tid == 0) {
    const int t = __hip_atomic_fetch_add(&g_bar_count, 1, __ATOMIC_RELAXED,
                                         __HIP_MEMORY_SCOPE_AGENT);
    const int target = (t / NBLK + 1) * NBLK;
    while (__hip_atomic_load(&g_bar_count, __ATOMIC_RELAXED,
                             __HIP_MEMORY_SCOPE_AGENT) < target) {
      __builtin_amdgcn_s_sleep(1);
    }
  }
  __syncthreads();
}

struct Ptrs { const float *x, *W1, *b1, *W2, *b2, *W3, *b3; };

// One drift evaluation, 3 phases. SIDX: 0 = f(y) (k1); 1..5 = k2..k6 stage
// inputs; 6 = y5/B-row (persists y5, computes k7 + embedded error).
template<int SIDX, bool DO_ERR>
__device__ void run_stage(const int tid, const int bid, const Ptrs& P,
                          const float* ycur, const float heff,
                          const float* k1p, float* outk, float* y5buf,
                          float* sA, float4* sRed)
{
  const int cc      = bid >> 4;          // col chunk (16 x 32 cols of W1)
  const int rowbase = (bid & 15) * RCH;  // row chunk (16 x 4096 rows)

  // ---------- Phase A: GEMV1 partials ----------
  {
    // each thread builds 4 consecutive stage-input elements (coherent loads)
    const int j4 = tid * 4;
    const int i  = rowbase + j4;
    float v0, v1, v2, v3;
    { const float2 a = cload2(ycur + i), b = cload2(ycur + i + 2);
      v0 = a.x; v1 = a.y; v2 = b.x; v3 = b.y; }
    if constexpr (SIDX > 0) {
      const float* kp[6] = {k1p, g_k2, g_k3, g_k4, g_k5, g_k6};
      float s0 = 0.f, s1 = 0.f, s2 = 0.f, s3 = 0.f;
      #pragma unroll
      for (int m = 0; m < 6; ++m) {
        const float cf = COEFC[SIDX - 1][m];   // compile-time after unroll
        if (cf != 0.f) {
          const float2 a = cload2(kp[m] + i), b = cload2(kp[m] + i + 2);
          s0 += cf * a.x; s1 += cf * a.y; s2 += cf * b.x; s3 += cf * b.y;
        }
      }
      v0 += heff * s0; v1 += heff * s1; v2 += heff * s2; v3 += heff * s3;
    }
    sA[j4 + 0] = v0; sA[j4 + 1] = v1; sA[j4 + 2] = v2; sA[j4 + 3] = v3;
    if constexpr (SIDX == 6) {
      if (cc == 0) { cstore2(y5buf + i, v0, v1); cstore2(y5buf + i + 2, v2, v3); }
    }
    __syncthreads();
    const int q = tid & 7, rg = tid >> 3;
    const int col = cc * 32 + q * 4;
    const float* wp = P.W1 + (size_t)rowbase * NH + col;
    float4 a0 = make_float4(0.f, 0.f, 0.f, 0.f);
    float4 a1 = make_float4(0.f, 0.f, 0.f, 0.f);
    #pragma unroll
    for (int it = 0; it < 16; ++it) {          // dual load streams
      const int r0 = rg + it * 256, r1 = r0 + 128;
      const float y0v = sA[r0], y1v = sA[r1];
      const float4 w0 = ld4(wp + (size_t)r0 * NH);
      const float4 w1 = ld4(wp + (size_t)r1 * NH);
      a0.x += y0v * w0.x; a0.y += y0v * w0.y; a0.z += y0v * w0.z; a0.w += y0v * w0.w;
      a1.x += y1v * w1.x; a1.y += y1v * w1.y; a1.z += y1v * w1.z; a1.w += y1v * w1.w;
    }
    f4acc(a0, a1);
    sRed[tid] = a0;
    __syncthreads();
    for (int off = 512; off >= 8; off >>= 1) {
      if (tid < off) { float4 a = sRed[tid]; f4acc(a, sRed[tid + off]); sRed[tid] = a; }
      __syncthreads();
    }
    if (tid < 8) {
      const float4 v = sRed[tid];
      float* dst = &g_ypart[bid & 15][cc * 32 + tid * 4];
      cstore2(dst, v.x, v.y); cstore2(dst + 2, v.z, v.w);
    }
  }
  gbar(tid);

  // ---------- Phase B: h1 = tanh(sum partials + b1); h2pre = h1 @ W2 ----------
  if (bid < 8) {
    if (tid < NH) {
      float pre = P.b1[tid];
      #pragma unroll
      for (int rc = 0; rc < 16; ++rc) pre += cload(&g_ypart[rc][tid]);
      #pragma unroll
      for (int rc = 0; rc < 16; ++rc) pre += cload(&g_ipart[rc][tid]);
      sA[tid] = tanhf(pre);
    }
    __syncthreads();
    float* sB = (float*)sRed;
    const int cl = tid & 63, kg = tid >> 6;    // 16 k-groups x 64 cols
    const int c = bid * 64 + cl;
    float acc = 0.f;
    #pragma unroll
    for (int m = 0; m < 32; ++m) {
      const int k = kg * 32 + m;
      acc += sA[k] * P.W2[(size_t)k * NH + c];
    }
    sB[tid] = acc;
    __syncthreads();
    for (int off = 512; off >= 64; off >>= 1) {
      if (tid < off) sB[tid] += sB[tid + off];
      __syncthreads();
    }
    if (tid < 64) cstore(&g_h2v[bid * 64 + tid], sB[tid]);
  }
  gbar(tid);

  // ---------- Phase C: outk[n] = tanh(h2pre+b2) @ W3 + b3 ----------
  {
    if (tid < NH) sA[tid] = tanhf(cload(&g_h2v[tid]) + P.b2[tid]);
    __syncthreads();
    const int cl = tid & 63, kg = tid >> 6;    // 16 k-groups x 64 col-quads
    const int n = bid * 256 + cl * 4;
    float4 a0 = make_float4(0.f, 0.f, 0.f, 0.f);
    float4 a1 = make_float4(0.f, 0.f, 0.f, 0.f);
    #pragma unroll
    for (int m = 0; m < 16; ++m) {             // dual streams
      const int k0 = kg * 32 + m, k1i = k0 + 16;
      const float h0 = sA[k0], h1 = sA[k1i];
      const float4 w0 = ld4(P.W3 + (size_t)k0 * NN + n);
      const float4 w1 = ld4(P.W3 + (size_t)k1i * NN + n);
      a0.x += h0 * w0.x; a0.y += h0 * w0.y; a0.z += h0 * w0.z; a0.w += h0 * w0.w;
      a1.x += h1 * w1.x; a1.y += h1 * w1.y; a1.z += h1 * w1.z; a1.w += h1 * w1.w;
    }
    f4acc(a0, a1);
    sRed[tid] = a0;
    __syncthreads();
    for (int off = 512; off >= 64; off >>= 1) {
      if (tid < off) { float4 a = sRed[tid]; f4acc(a, sRed[tid + off]); sRed[tid] = a; }
      __syncthreads();
    }
    float ss = 0.f;
    if (tid < 64) {
      float4 r = sRed[tid];
      const int nn = bid * 256 + tid * 4;
      const float4 b3v = ld4(P.b3 + nn);
      r.x += b3v.x; r.y += b3v.y; r.z += b3v.z; r.w += b3v.w;
      cstore2(outk + nn, r.x, r.y); cstore2(outk + nn + 2, r.z, r.w);
      if constexpr (DO_ERR) {                  // fused embedded-error pass (r == k7)
        const float4 k1v = cload4(k1p + nn);
        const float4 k3v = cload4(g_k3 + nn);
        const float4 k4v = cload4(g_k4 + nn);
        const float4 k5v = cload4(g_k5 + nn);
        const float4 k6v = cload4(g_k6 + nn);
        const float4 yv  = cload4(ycur + nn);
        const float4 y5v = cload4(y5buf + nn);
        #define ERRC(c) { \
          const float e = heff*(CE1*k1v.c + CE3*k3v.c + CE4*k4v.c + \
                                CE5*k5v.c + CE6*k6v.c + CE7*r.c); \
          const float sc = F_ATOL + F_RTOL*fmaxf(fabsf(yv.c), fabsf(y5v.c)); \
          const float qq = e / sc; ss += qq * qq; }
        ERRC(x) ERRC(y) ERRC(z) ERRC(w)
        #undef ERRC
      }
    }
    if constexpr (DO_ERR) {                    // deterministic per-block partial
      __syncthreads();
      if (tid < 64) sA[tid] = ss;
      __syncthreads();
      if (tid == 0) {
        float s = 0.f;
        for (int i2 = 0; i2 < 64; ++i2) s += sA[i2];
        cstore(&g_errpart[bid], s);
      }
    }
  }
  gbar(tid);
}

__global__ void __launch_bounds__(NTHR, 4)
ode_kernel(const float* __restrict__ x,  const float* __restrict__ W1,
           const float* __restrict__ b1, const float* __restrict__ W2,
           const float* __restrict__ b2, const float* __restrict__ W3,
           const float* __restrict__ b3, float* __restrict__ out)
{
  const int tid = threadIdx.x, bid = blockIdx.x;
  __shared__ float  sA[RCH];
  __shared__ float4 sRed[NTHR];

  Ptrs P{x, W1, b1, W2, b2, W3, b3};

  // ---- init: y0 = y = x[:,3] (coherent stores); I-partials (all blocks) ----
  {
    const int gi = bid * NTHR + tid;
    if (gi < NN / 4) {                          // blocks 0..15
      const int i = gi * 4;
      const float a = x[(size_t)(i + 0) * 8 + 3];
      const float b = x[(size_t)(i + 1) * 8 + 3];
      const float c = x[(size_t)(i + 2) * 8 + 3];
      const float d = x[(size_t)(i + 3) * 8 + 3];
      cstore2(g_y0 + i, a, b);   cstore2(g_y0 + i + 2, c, d);
      cstore2(g_bufA + i, a, b); cstore2(g_bufA + i + 2, c, d);
    }
  }
  {
    const int cc = bid >> 4;
    const int rowbase = (bid & 15) * 1024;     // 16 chunks x 1024 input rows
    if (tid < 1024) sA[tid] = x[(size_t)(rowbase + tid) * 8 + 4];
    __syncthreads();
    const int q = tid & 7, rg = tid >> 3;
    const int col = cc * 32 + q * 4;
    const float* wp = W1 + (size_t)(NN + rowbase) * NH + col;
    float4 acc = make_float4(0.f, 0.f, 0.f, 0.f);
    #pragma unroll
    for (int it = 0; it < 8; ++it) {
      const int r = rg + it * 128;
      const float yv = sA[r];
      const float4 w = ld4(wp + (size_t)r * NH);
      acc.x += yv * w.x; acc.y += yv * w.y; acc.z += yv * w.z; acc.w += yv * w.w;
    }
    sRed[tid] = acc;
    __syncthreads();
    for (int off = 512; off >= 8; off >>= 1) {
      if (tid < off) { float4 a = sRed[tid]; f4acc(a, sRed[tid + off]); sRed[tid] = a; }
      __syncthreads();
    }
    if (tid < 8) {
      const float4 v = sRed[tid];
      float* dst = &g_ipart[bid & 15][cc * 32 + tid * 4];
      cstore2(dst, v.x, v.y); cstore2(dst + 2, v.z, v.w);
    }
  }
  gbar(tid);

  // ---- dopri5 ----
  float tcur = 0.f, hcur = F_T;
  float* yp  = g_bufA;  float* y5p = g_bufB;
  float* k1p = g_kA;    float* k7p = g_kB;

  // k1 = f(y0) once; thereafter k1_next = take ? k7 : k1 (FSAL, bitwise = ref)
  run_stage<0, false>(tid, bid, P, yp, 0.f, k1p, k1p, y5p, sA, sRed);

  for (int attempt = 0; attempt < 8; ++attempt) {
    if (tcur >= F_T) break;   // grid-uniform
    const float heff = fminf(hcur, F_T - tcur);

    run_stage<1, false>(tid, bid, P, yp, heff, k1p, g_k2, y5p, sA, sRed);
    run_stage<2, false>(tid, bid, P, yp, heff, k1p, g_k3, y5p, sA, sRed);
    run_stage<3, false>(tid, bid, P, yp, heff, k1p, g_k4, y5p, sA, sRed);
    run_stage<4, false>(tid, bid, P, yp, heff, k1p, g_k5, y5p, sA, sRed);
    run_stage<5, false>(tid, bid, P, yp, heff, k1p, g_k6, y5p, sA, sRed);
    run_stage<6, true >(tid, bid, P, yp, heff, k1p, k7p,  y5p, sA, sRed);

    // deterministic err^2: identical fixed-order LDS tree in every block
    float e2;
    {
      float* sB = (float*)sRed;
      if (tid < NBLK) sB[tid] = cload(&g_errpart[tid]);
      __syncthreads();
      for (int off = 128; off >= 1; off >>= 1) {
        if (tid < off) sB[tid] += sB[tid + off];
        __syncthreads();
      }
      e2 = sB[0];
      __syncthreads();
    }

    const float err_norm = sqrtf(e2 * (1.0f / 65536.0f) + 1e-16f);
    const bool accept = err_norm <= 1.0f;
    float fac = 0.9f * powf(err_norm + 1e-10f, -0.2f);
    fac = fminf(fmaxf(fac, 0.2f), 5.0f);
    if (accept) {
      tcur += heff;
      float* tp = yp;  yp  = y5p; y5p = tp;
      tp = k1p; k1p = k7p; k7p = tp;   // FSAL: new k1 == old k7
    }
    hcur = heff * fac;
  }

  if (tid < 256) {
    const int i = bid * 256 + tid;
    out[i] = (cload(yp + i) - cload(g_y0 + i)) / F_T;
  }
}

extern "C" void kernel_launch(void* const* d_in, const int* in_sizes, int n_in,
                              void* d_out, int out_size, void* d_ws, size_t ws_size,
                              hipStream_t stream) {
  const float* x  = (const float*)d_in[0];
  const float* W1 = (const float*)d_in[1];
  const float* b1 = (const float*)d_in[2];
  const float* W2 = (const float*)d_in[3];
  const float* b2 = (const float*)d_in[4];
  const float* W3 = (const float*)d_in[5];
  const float* b3 = (const float*)d_in[6];
  float* out = (float*)d_out;
  void* args[] = {(void*)&x, (void*)&W1, (void*)&b1, (void*)&W2, (void*)&b2,
                  (void*)&W3, (void*)&b3, (void*)&out};
  hipLaunchCooperativeKernel((void*)ode_kernel, dim3(NBLK), dim3(NTHR), args, 0, stream);
}